// Round 2
// baseline (9333.263 us; speedup 1.0000x reference)
//
#include <hip/hip_runtime.h>
#include <math.h>

constexpr int DIM = 2048, EMB = 512, HID = 512, VOC = 32000, TLEN = 32, G3 = 1536;
constexpr int NB = 256;     // blocks; 1/CU guaranteed resident (grid <= 256 CUs)
constexpr int NT = 256;     // threads/block (4 waves)
constexpr int ROWS = 125;   // vocab rows per block: 256*125 = 32000
constexpr unsigned MAGIC = 0x13579BDFu;

// ---- workspace layout (floats) ----
constexpr size_t W_H1  = 0;                         // [8][2048]
constexpr size_t W_H2  = W_H1 + 8 * 2048;           // [8][2048]
constexpr size_t W_IMG = W_H2 + 8 * 2048;           // [8][512]
constexpr size_t W_GI  = W_IMG + 8 * 512;           // [8][1536]
constexpr size_t W_GH  = W_GI + 8 * 1536;           // [8][1536]
constexpr size_t W_S   = W_GH + 8 * 1536;           // [8][512]  (sum e)*img, unnormalized
constexpr size_t W_RSP = W_S + 8 * 512;             // [256][8] rowsum partials
constexpr size_t W_RST = W_RSP + (size_t)NB * 8;    // [33][8]  rowsum totals
constexpr size_t W_EP  = W_RST + 33 * 8;            // [256][4096] e partials (~4MB)
constexpr size_t W_FLG = W_EP + (size_t)NB * 4096;  // 169 uints

__device__ __forceinline__ float dot4(float4 a, float4 b) {
  return a.x * b.x + a.y * b.y + a.z * b.z + a.w * b.w;
}
__device__ __forceinline__ float4 fma4(float4 acc, float s, float4 v) {
  acc.x += s * v.x; acc.y += s * v.y; acc.z += s * v.z; acc.w += s * v.w; return acc;
}
__device__ __forceinline__ float4 add4(float4 a, float4 b) {
  a.x += b.x; a.y += b.y; a.z += b.z; a.w += b.w; return a;
}
__device__ __forceinline__ float sigm(float x) { return 1.0f / (1.0f + __expf(-x)); }
__device__ __forceinline__ float gru_h(float ir, float iz, float in_, float hr, float hz,
                                       float hn, float hp) {
  float r = sigm(ir + hr), z = sigm(iz + hz);
  float n = tanhf(in_ + r * hn);
  return (1.0f - z) * n + z * hp;
}
__device__ __forceinline__ float selLane8(const float pb[8]) {
  int lane = threadIdx.x & 63;
  float r = 0.0f;
#pragma unroll
  for (int b = 0; b < 8; b++) r = (lane == b) ? pb[b] : r;
  return r;
}

// wave computes dot of one KLEN-long weight row against 8 batch rows of xsrc
template <int KLEN>
__device__ __forceinline__ void rowdot8(const float* __restrict__ wrow,
                                        const float* __restrict__ xsrc, float pb[8]) {
  constexpr int PER = KLEN / 64;
  constexpr int NF4 = PER / 4;
  int lane = threadIdx.x & 63;
  int k0 = lane * PER;
  const float4* w4 = (const float4*)(wrow + k0);
  float4 wv[NF4];
#pragma unroll
  for (int i = 0; i < NF4; i++) wv[i] = w4[i];
#pragma unroll
  for (int b = 0; b < 8; b++) {
    const float4* x4 = (const float4*)(xsrc + b * KLEN + k0);
    float s = 0.0f;
#pragma unroll
    for (int i = 0; i < NF4; i++) s += dot4(x4[i], wv[i]);
    pb[b] = s;
  }
#pragma unroll
  for (int m = 1; m < 64; m <<= 1) {
#pragma unroll
    for (int b = 0; b < 8; b++) pb[b] += __shfl_xor(pb[b], m, 64);
  }
}

__device__ __forceinline__ void pollGE(const unsigned* p, unsigned tgt) {
  if (threadIdx.x == 0) {
    while (__hip_atomic_load(p, __ATOMIC_ACQUIRE, __HIP_MEMORY_SCOPE_AGENT) < tgt)
      __builtin_amdgcn_s_sleep(8);
  }
  __syncthreads();
  __threadfence();  // acquire side: invalidate caches so fresh data is seen
}
__device__ __forceinline__ void postAdd(unsigned* p) {
  __threadfence();  // release side: make this block's stores agent-visible
  __syncthreads();
  if (threadIdx.x == 0)
    __hip_atomic_fetch_add(p, 1u, __ATOMIC_RELEASE, __HIP_MEMORY_SCOPE_AGENT);
}

__global__ void __launch_bounds__(NT, 1)
InformedRnnSenderFixedLengthGS_48704929136907_kernel(
    const float* __restrict__ x, const float* __restrict__ enc_w,
    const float* __restrict__ enc_b, const float* __restrict__ out_w,
    const float* __restrict__ out_b, const float* __restrict__ emb_out,
    const float* __restrict__ emb_in, const float* __restrict__ ph,
    const float* __restrict__ w_ih, const float* __restrict__ b_ih,
    const float* __restrict__ w_hh, const float* __restrict__ b_hh,
    const float* __restrict__ gum, float* __restrict__ out, float* __restrict__ ws) {
  const int tid = threadIdx.x, blk = blockIdx.x;
  const int lane = tid & 63, wave = tid >> 6;

  float* h1 = ws + W_H1;
  float* h2 = ws + W_H2;
  float* img = ws + W_IMG;
  float* gi = ws + W_GI;
  float* gh = ws + W_GH;
  float* sbuf = ws + W_S;
  float* rs_part = ws + W_RSP;
  float* rs_tot = ws + W_RST;
  float* e_part = ws + W_EP;
  unsigned* flg = (unsigned*)(ws + W_FLG);
  unsigned* arrive = flg;         // [33]
  unsigned* sdone = flg + 33;     // [33]
  unsigned* gidone = flg + 66;    // [33]
  unsigned* ghdone = flg + 99;    // [33]
  unsigned* rsready = flg + 132;  // [33]
  unsigned* bar = flg + 165;      // [3]
  unsigned* ready = flg + 168;    // [1]

  __shared__ float h_lds[4096];    // [8][512] hidden state (replicated per block)
  __shared__ float red_e[4096];    // scratch reductions
  __shared__ float p_lds[ROWS * 8];
  __shared__ float gum_lds[ROWS * 8];
  __shared__ float red_rs[32];
  __shared__ float inv_lds[8];

  // ---- init handshake: block 0 zeroes flags, then releases MAGIC ----
  if (blk == 0) {
    if (tid < 169) flg[tid] = 0u;
    __threadfence();
    __syncthreads();
    if (tid == 0)
      __hip_atomic_store(ready, MAGIC, __ATOMIC_RELEASE, __HIP_MEMORY_SCOPE_AGENT);
  }
  if (tid == 0) {
    while (__hip_atomic_load(ready, __ATOMIC_ACQUIRE, __HIP_MEMORY_SCOPE_AGENT) != MAGIC)
      __builtin_amdgcn_s_sleep(8);
  }
  __syncthreads();
  __threadfence();

  // ---- E1: h1 = tanh(x @ enc_w0^T + b0); 2048 rows, 8/block, 2/wave ----
#pragma unroll
  for (int rr = 0; rr < 2; rr++) {
    int o = blk * 8 + wave * 2 + rr;
    float pb[8];
    rowdot8<2048>(enc_w + (size_t)o * DIM, x, pb);
    float eb = enc_b[o];
#pragma unroll
    for (int b = 0; b < 8; b++) pb[b] = tanhf(pb[b] + eb);
    float myv = selLane8(pb);
    if (lane < 8) h1[lane * DIM + o] = myv;
  }
  postAdd(&bar[0]); pollGE(&bar[0], (unsigned)NB);

  // ---- E2 ----
#pragma unroll
  for (int rr = 0; rr < 2; rr++) {
    int o = blk * 8 + wave * 2 + rr;
    float pb[8];
    rowdot8<2048>(enc_w + (size_t)DIM * DIM + (size_t)o * DIM, h1, pb);
    float eb = enc_b[DIM + o];
#pragma unroll
    for (int b = 0; b < 8; b++) pb[b] = tanhf(pb[b] + eb);
    float myv = selLane8(pb);
    if (lane < 8) h2[lane * DIM + o] = myv;
  }
  postAdd(&bar[1]); pollGE(&bar[1], (unsigned)NB);

  // ---- E3: img_feats (blk<64), gh0 (64..127), gi0 (128..191) ----
  if (blk < 64) {
#pragma unroll
    for (int rr = 0; rr < 2; rr++) {
      int o = blk * 8 + wave * 2 + rr;  // 0..511
      float pb[8];
      rowdot8<2048>(out_w + (size_t)o * DIM, h2, pb);
      float ob = out_b[o];
#pragma unroll
      for (int b = 0; b < 8; b++) pb[b] += ob;
      float myv = selLane8(pb);
      if (lane < 8) img[lane * EMB + o] = myv;
    }
  } else if (blk < 128) {
    int local = blk - 64;
    int kk = lane * 8;
    float4 p0 = *(const float4*)(ph + kk);
    float4 p1 = *(const float4*)(ph + kk + 4);
    for (int r = 0; r < 6; r++) {
      int j = local * 24 + wave * 6 + r;
      const float4* w4 = (const float4*)(w_hh + (size_t)j * HID + kk);
      float s = dot4(p0, w4[0]) + dot4(p1, w4[1]);
#pragma unroll
      for (int m = 1; m < 64; m <<= 1) s += __shfl_xor(s, m, 64);
      float val = s + b_hh[j];
      if (lane < 8) gh[lane * G3 + j] = val;
    }
  } else if (blk < 192) {
    int local = blk - 128;
    for (int r = 0; r < 6; r++) {
      int j = local * 24 + wave * 6 + r;
      float val = b_ih[j];  // e0 == 0
      if (lane < 8) gi[lane * G3 + j] = val;
    }
  }
  for (int i = tid; i < 4096; i += NT) h_lds[i] = ph[i & 511];
  __syncthreads();
  postAdd(&bar[2]); pollGE(&bar[2], (unsigned)NB);

  const int v0 = blk * ROWS;
  const int k0 = lane * 8;
  const int rbeg = (wave * ROWS) / 4, rend = ((wave + 1) * ROWS) / 4;

  for (int t = 0; t < TLEN; ++t) {
    // 0) coalesced gumbel tile load (overlaps the gate wait)
    for (int i = tid; i < ROWS * 8; i += NT) {
      int b = i / ROWS, vl = i - b * ROWS;
      gum_lds[vl * 8 + b] = gum[(size_t)t * (8 * VOC) + (size_t)b * VOC + v0 + vl];
    }
    // 1) wait for this step's gates
    if (t > 0) {
      if (tid == 0) {
        while (__hip_atomic_load(&gidone[t], __ATOMIC_ACQUIRE, __HIP_MEMORY_SCOPE_AGENT) < 64u)
          __builtin_amdgcn_s_sleep(8);
        while (__hip_atomic_load(&ghdone[t], __ATOMIC_ACQUIRE, __HIP_MEMORY_SCOPE_AGENT) < 64u)
          __builtin_amdgcn_s_sleep(8);
      }
      __syncthreads();
      __threadfence();
    }
    // 2) GRU elementwise update (redundant per block; h in LDS)
    {
      int idx = tid * 16;
      int b = idx >> 9, k = idx & 511;
      const float* gib = gi + b * G3 + k;
      const float* ghb = gh + b * G3 + k;
      float* hpp = h_lds + b * 512 + k;
#pragma unroll
      for (int q = 0; q < 16; q += 4) {
        float4 ir = *(const float4*)(gib + q);
        float4 iz = *(const float4*)(gib + 512 + q);
        float4 in_ = *(const float4*)(gib + 1024 + q);
        float4 hr = *(const float4*)(ghb + q);
        float4 hz = *(const float4*)(ghb + 512 + q);
        float4 hn = *(const float4*)(ghb + 1024 + q);
        float4 hp = *(const float4*)(hpp + q);
        float4 hv;
        hv.x = gru_h(ir.x, iz.x, in_.x, hr.x, hz.x, hn.x, hp.x);
        hv.y = gru_h(ir.y, iz.y, in_.y, hr.y, hz.y, hn.y, hp.y);
        hv.z = gru_h(ir.z, iz.z, in_.z, hr.z, hz.z, hn.z, hp.z);
        hv.w = gru_h(ir.w, iz.w, in_.w, hr.w, hz.w, hn.w, hp.w);
        *(float4*)(hpp + q) = hv;
      }
    }
    __syncthreads();
    // 3) per-lane h fragments
    float4 hf[8][2];
#pragma unroll
    for (int b = 0; b < 8; b++) {
      hf[b][0] = *(const float4*)(h_lds + b * 512 + k0);
      hf[b][1] = *(const float4*)(h_lds + b * 512 + k0 + 4);
    }
    // 4) vocab rows: logits -> +gumbel -> exp -> p, rowsum, e accumulation
    float4 ea[8][2];
#pragma unroll
    for (int b = 0; b < 8; b++) { ea[b][0] = make_float4(0, 0, 0, 0); ea[b][1] = make_float4(0, 0, 0, 0); }
    float sums[8] = {0, 0, 0, 0, 0, 0, 0, 0};
    for (int r = rbeg; r < rend; ++r) {
      int v = v0 + r;
      const float4* wo = (const float4*)(emb_out + (size_t)v * EMB + k0);
      float4 a0 = wo[0], a1 = wo[1];
      float pb[8];
#pragma unroll
      for (int b = 0; b < 8; b++) pb[b] = dot4(hf[b][0], a0) + dot4(hf[b][1], a1);
#pragma unroll
      for (int m = 1; m < 64; m <<= 1) {
#pragma unroll
        for (int b = 0; b < 8; b++) pb[b] += __shfl_xor(pb[b], m, 64);
      }
#pragma unroll
      for (int b = 0; b < 8; b++) {
        pb[b] = __expf(pb[b] + gum_lds[r * 8 + b]);
        sums[b] += pb[b];
      }
      if (lane == 0) {
        *(float4*)&p_lds[r * 8] = make_float4(pb[0], pb[1], pb[2], pb[3]);
        *(float4*)&p_lds[r * 8 + 4] = make_float4(pb[4], pb[5], pb[6], pb[7]);
      }
      const float4* wi = (const float4*)(emb_in + (size_t)v * EMB + k0);
      float4 i0 = wi[0], i1 = wi[1];
#pragma unroll
      for (int b = 0; b < 8; b++) {
        ea[b][0] = fma4(ea[b][0], pb[b], i0);
        ea[b][1] = fma4(ea[b][1], pb[b], i1);
      }
    }
    // 5) cross-wave e reduce (phased over 4 waves)
    for (int w = 0; w < 4; w++) {
      if (wave == w) {
#pragma unroll
        for (int b = 0; b < 8; b++) {
          float4* d = (float4*)&red_e[b * 512 + k0];
          if (w == 0) { d[0] = ea[b][0]; d[1] = ea[b][1]; }
          else { d[0] = add4(d[0], ea[b][0]); d[1] = add4(d[1], ea[b][1]); }
        }
      }
      __syncthreads();
    }
    if (lane == 0) {
      *(float4*)&red_rs[wave * 8] = make_float4(sums[0], sums[1], sums[2], sums[3]);
      *(float4*)&red_rs[wave * 8 + 4] = make_float4(sums[4], sums[5], sums[6], sums[7]);
    }
    __syncthreads();
    // 6) publish e partial + rowsum partial
    {
      float* ep = e_part + (size_t)blk * 4096;
      for (int i = tid; i < 1024; i += NT) ((float4*)ep)[i] = ((const float4*)red_e)[i];
      if (tid == 0) {
        float4 lo = add4(add4(*(float4*)&red_rs[0], *(float4*)&red_rs[8]),
                         add4(*(float4*)&red_rs[16], *(float4*)&red_rs[24]));
        float4 hi = add4(add4(*(float4*)&red_rs[4], *(float4*)&red_rs[12]),
                         add4(*(float4*)&red_rs[20], *(float4*)&red_rs[28]));
        *(float4*)&rs_part[blk * 8] = lo;
        *(float4*)&rs_part[blk * 8 + 4] = hi;
      }
    }
    postAdd(&arrive[t]);

    // ---- roles ----
    if (blk < 64 && t < TLEN - 1) {  // e-partial reducers -> sbuf = (sum e) * img
      pollGE(&arrive[t], (unsigned)NB);
      int og = blk * 64 + (tid & 63);
      int part = tid >> 6;  // 0..3, 64 partials each
      const float* epp = e_part + og;
      float ssum = 0.0f;
      int ibeg = part * 64;
#pragma unroll 8
      for (int i = ibeg; i < ibeg + 64; ++i) ssum += epp[(size_t)i * 4096];
      red_e[tid] = ssum;
      __syncthreads();
      if (tid < 64) {
        float tot = red_e[tid] + red_e[tid + 64] + red_e[tid + 128] + red_e[tid + 192];
        int og2 = blk * 64 + tid;
        sbuf[og2] = tot * img[og2];
      }
      postAdd(&sdone[t]);
    }
    if (blk == 64) {  // rowsum reducer
      pollGE(&arrive[t], (unsigned)NB);
      int b = tid & 7, g = tid >> 3;  // g in 0..31
      float s = 0.0f;
#pragma unroll
      for (int i = 0; i < 8; i++) s += rs_part[(size_t)(g + 32 * i) * 8 + b];
      red_e[tid] = s;
      __syncthreads();
      if (tid < 8) {
        float tot = 0.0f;
#pragma unroll
        for (int g2 = 0; g2 < 32; ++g2) tot += red_e[g2 * 8 + tid];
        rs_tot[t * 8 + tid] = tot;
      }
      __threadfence();
      __syncthreads();
      if (tid == 0)
        __hip_atomic_store(&rsready[t], 1u, __ATOMIC_RELEASE, __HIP_MEMORY_SCOPE_AGENT);
    }
    if (blk >= 65 && blk < 129 && t < TLEN - 1) {  // gi producers
      pollGE(&sdone[t], 64u);
      pollGE(&rsready[t], 1u);
      float inv[8];
#pragma unroll
      for (int b = 0; b < 8; b++) inv[b] = 1.0f / rs_tot[t * 8 + b];
      float4 sf[8][2];
#pragma unroll
      for (int b = 0; b < 8; b++) {
        sf[b][0] = *(const float4*)(sbuf + b * 512 + k0);
        sf[b][1] = *(const float4*)(sbuf + b * 512 + k0 + 4);
      }
      int local = blk - 65;
      for (int r = 0; r < 6; r++) {
        int j = local * 24 + wave * 6 + r;
        const float4* w4 = (const float4*)(w_ih + (size_t)j * HID + k0);
        float4 w0 = w4[0], w1 = w4[1];
        float pb[8];
#pragma unroll
        for (int b = 0; b < 8; b++) pb[b] = dot4(sf[b][0], w0) + dot4(sf[b][1], w1);
#pragma unroll
        for (int m = 1; m < 64; m <<= 1) {
#pragma unroll
          for (int b = 0; b < 8; b++) pb[b] += __shfl_xor(pb[b], m, 64);
        }
        float bi = b_ih[j];
#pragma unroll
        for (int b = 0; b < 8; b++) pb[b] = inv[b] * pb[b] + bi;
        float myv = selLane8(pb);
        if (lane < 8) gi[lane * G3 + j] = myv;
      }
      postAdd(&gidone[t + 1]);
    }
    if (blk >= 129 && blk < 193 && t < TLEN - 1) {  // gh producers
      pollGE(&arrive[t], (unsigned)NB);
      int local = blk - 129;
      for (int r = 0; r < 6; r++) {
        int j = local * 24 + wave * 6 + r;
        const float4* w4 = (const float4*)(w_hh + (size_t)j * HID + k0);
        float4 w0 = w4[0], w1 = w4[1];
        float pb[8];
#pragma unroll
        for (int b = 0; b < 8; b++) pb[b] = dot4(hf[b][0], w0) + dot4(hf[b][1], w1);
#pragma unroll
        for (int m = 1; m < 64; m <<= 1) {
#pragma unroll
          for (int b = 0; b < 8; b++) pb[b] += __shfl_xor(pb[b], m, 64);
        }
        float bh = b_hh[j];
#pragma unroll
        for (int b = 0; b < 8; b++) pb[b] += bh;
        float myv = selLane8(pb);
        if (lane < 8) gh[lane * G3 + j] = myv;
      }
      postAdd(&ghdone[t + 1]);
    }
    // ---- x_t normalize + write (all blocks) ----
    pollGE(&rsready[t], 1u);
    if (tid < 8) inv_lds[tid] = 1.0f / rs_tot[t * 8 + tid];
    __syncthreads();
    {
      for (int i = tid; i < ROWS * 8; i += NT) {
        int b = i / ROWS, vl = i - b * ROWS;
        out[(size_t)b * ((size_t)TLEN * VOC) + (size_t)t * VOC + v0 + vl] =
            p_lds[vl * 8 + b] * inv_lds[b];
      }
    }
  }
}

extern "C" void kernel_launch(void* const* d_in, const int* in_sizes, int n_in,
                              void* d_out, int out_size, void* d_ws, size_t ws_size,
                              hipStream_t stream) {
  const float* x = (const float*)d_in[0];
  const float* enc_w = (const float*)d_in[1];
  const float* enc_b = (const float*)d_in[2];
  const float* out_w = (const float*)d_in[3];
  const float* out_b = (const float*)d_in[4];
  const float* emb_out = (const float*)d_in[5];
  const float* emb_in = (const float*)d_in[6];
  const float* ph = (const float*)d_in[7];
  const float* w_ih = (const float*)d_in[8];
  const float* b_ih = (const float*)d_in[9];
  const float* w_hh = (const float*)d_in[10];
  const float* b_hh = (const float*)d_in[11];
  const float* gum = (const float*)d_in[12];
  float* out = (float*)d_out;
  float* ws = (float*)d_ws;

  InformedRnnSenderFixedLengthGS_48704929136907_kernel<<<dim3(NB), dim3(NT), 0, stream>>>(
      x, enc_w, enc_b, out_w, out_b, emb_out, emb_in, ph, w_ih, b_ih, w_hh, b_hh, gum,
      out, ws);
}

// Round 3
// 7892.068 us; speedup vs baseline: 1.1826x; 1.1826x over previous
//
#include <hip/hip_runtime.h>
#include <math.h>

constexpr int DIM = 2048, EMB = 512, HID = 512, VOC = 32000, TLEN = 32, G3 = 1536;
constexpr int NB = 256;     // blocks; 1/CU guaranteed resident (grid <= 256 CUs)
constexpr int NT = 256;     // threads/block (4 waves) -> 1 wave/SIMD, ILP must hide latency
constexpr int ROWS = 125;   // vocab rows per block: 256*125 = 32000
constexpr unsigned MAGIC = 0x13579BDFu;

// ---- workspace layout (floats) ----
constexpr size_t W_H1  = 0;                         // [8][2048]
constexpr size_t W_H2  = W_H1 + 8 * 2048;           // [8][2048]
constexpr size_t W_IMG = W_H2 + 8 * 2048;           // [8][512]
constexpr size_t W_GI  = W_IMG + 8 * 512;           // [8][1536]
constexpr size_t W_GH  = W_GI + 8 * 1536;           // [8][1536]
constexpr size_t W_S   = W_GH + 8 * 1536;           // [8][512]  (sum e)*img, unnormalized
constexpr size_t W_RSP = W_S + 8 * 512;             // [256][8] rowsum partials
constexpr size_t W_RST = W_RSP + (size_t)NB * 8;    // [33][8]  rowsum totals
constexpr size_t W_EP  = W_RST + 33 * 8;            // [64 chunks][256 src][64] e partials (4MB)
constexpr size_t W_FLG = W_EP + (size_t)NB * 4096;  // 169 uints

__device__ __forceinline__ float dot4(float4 a, float4 b) {
  return a.x * b.x + a.y * b.y + a.z * b.z + a.w * b.w;
}
__device__ __forceinline__ float4 fma4(float4 acc, float s, float4 v) {
  acc.x += s * v.x; acc.y += s * v.y; acc.z += s * v.z; acc.w += s * v.w; return acc;
}
__device__ __forceinline__ float4 add4(float4 a, float4 b) {
  a.x += b.x; a.y += b.y; a.z += b.z; a.w += b.w; return a;
}
__device__ __forceinline__ float sigm(float x) { return 1.0f / (1.0f + __expf(-x)); }
__device__ __forceinline__ float gru_h(float ir, float iz, float in_, float hr, float hz,
                                       float hn, float hp) {
  float r = sigm(ir + hr), z = sigm(iz + hz);
  float n = tanhf(in_ + r * hn);
  return (1.0f - z) * n + z * hp;
}
__device__ __forceinline__ float selLane8(const float pb[8]) {
  int lane = threadIdx.x & 63;
  float r = 0.0f;
#pragma unroll
  for (int b = 0; b < 8; b++) r = (lane == b) ? pb[b] : r;
  return r;
}

template <int KLEN>
__device__ __forceinline__ void rowdot8(const float* __restrict__ wrow,
                                        const float* __restrict__ xsrc, float pb[8]) {
  constexpr int PER = KLEN / 64;
  constexpr int NF4 = PER / 4;
  int lane = threadIdx.x & 63;
  int k0 = lane * PER;
  const float4* w4 = (const float4*)(wrow + k0);
  float4 wv[NF4];
#pragma unroll
  for (int i = 0; i < NF4; i++) wv[i] = w4[i];
#pragma unroll
  for (int b = 0; b < 8; b++) {
    const float4* x4 = (const float4*)(xsrc + b * KLEN + k0);
    float s = 0.0f;
#pragma unroll
    for (int i = 0; i < NF4; i++) s += dot4(x4[i], wv[i]);
    pb[b] = s;
  }
#pragma unroll
  for (int m = 1; m < 64; m <<= 1) {
#pragma unroll
    for (int b = 0; b < 8; b++) pb[b] += __shfl_xor(pb[b], m, 64);
  }
}

__device__ __forceinline__ void pollGE(const unsigned* p, unsigned tgt) {
  if (threadIdx.x == 0) {
    while (__hip_atomic_load(p, __ATOMIC_ACQUIRE, __HIP_MEMORY_SCOPE_AGENT) < tgt)
      __builtin_amdgcn_s_sleep(1);
  }
  __syncthreads();
  __threadfence();
}
__device__ __forceinline__ void postAdd(unsigned* p) {
  __threadfence();
  __syncthreads();
  if (threadIdx.x == 0)
    __hip_atomic_fetch_add(p, 1u, __ATOMIC_RELEASE, __HIP_MEMORY_SCOPE_AGENT);
}

// one vocab row: logits dot + butterfly + gumbel/exp + p store + e-accum
__device__ __forceinline__ void vocabRow(int r, float4 a0, float4 a1, float4 i0, float4 i1,
                                         const float4 hf[8][2], float4 ea[8][2],
                                         float sums[8], float* __restrict__ p_lds,
                                         const float* __restrict__ gum_lds) {
  int lane = threadIdx.x & 63;
  float pb[8];
#pragma unroll
  for (int b = 0; b < 8; b++) pb[b] = dot4(hf[b][0], a0) + dot4(hf[b][1], a1);
#pragma unroll
  for (int m = 1; m < 64; m <<= 1) {
#pragma unroll
    for (int b = 0; b < 8; b++) pb[b] += __shfl_xor(pb[b], m, 64);
  }
#pragma unroll
  for (int b = 0; b < 8; b++) {
    pb[b] = __expf(pb[b] + gum_lds[r * 8 + b]);
    sums[b] += pb[b];
  }
  if (lane == 0) {
    *(float4*)&p_lds[r * 8] = make_float4(pb[0], pb[1], pb[2], pb[3]);
    *(float4*)&p_lds[r * 8 + 4] = make_float4(pb[4], pb[5], pb[6], pb[7]);
  }
#pragma unroll
  for (int b = 0; b < 8; b++) {
    ea[b][0] = fma4(ea[b][0], pb[b], i0);
    ea[b][1] = fma4(ea[b][1], pb[b], i1);
  }
}

__global__ void __launch_bounds__(NT, 1)
InformedRnnSenderFixedLengthGS_48704929136907_kernel(
    const float* __restrict__ x, const float* __restrict__ enc_w,
    const float* __restrict__ enc_b, const float* __restrict__ out_w,
    const float* __restrict__ out_b, const float* __restrict__ emb_out,
    const float* __restrict__ emb_in, const float* __restrict__ ph,
    const float* __restrict__ w_ih, const float* __restrict__ b_ih,
    const float* __restrict__ w_hh, const float* __restrict__ b_hh,
    const float* __restrict__ gum, float* __restrict__ out, float* __restrict__ ws) {
  const int tid = threadIdx.x, blk = blockIdx.x;
  const int lane = tid & 63, wave = tid >> 6;

  float* h1 = ws + W_H1;
  float* h2 = ws + W_H2;
  float* img = ws + W_IMG;
  float* gi = ws + W_GI;
  float* gh = ws + W_GH;
  float* sbuf = ws + W_S;
  float* rs_part = ws + W_RSP;
  float* rs_tot = ws + W_RST;
  float* e_part = ws + W_EP;
  unsigned* flg = (unsigned*)(ws + W_FLG);
  unsigned* arrive = flg;         // [33]
  unsigned* sdone = flg + 33;     // [33]
  unsigned* gidone = flg + 66;    // [33]
  unsigned* ghdone = flg + 99;    // [33]
  unsigned* rsready = flg + 132;  // [33]
  unsigned* bar = flg + 165;      // [3]
  unsigned* ready = flg + 168;    // [1]

  __shared__ float h_lds[4096];
  __shared__ float red_e[4096];
  __shared__ float p_lds[ROWS * 8];
  __shared__ float gum_lds[ROWS * 8];
  __shared__ float red_rs[32];
  __shared__ float inv_lds[8];

  // ---- init handshake ----
  if (blk == 0) {
    if (tid < 169) flg[tid] = 0u;
    __threadfence();
    __syncthreads();
    if (tid == 0)
      __hip_atomic_store(ready, MAGIC, __ATOMIC_RELEASE, __HIP_MEMORY_SCOPE_AGENT);
  }
  if (tid == 0) {
    while (__hip_atomic_load(ready, __ATOMIC_ACQUIRE, __HIP_MEMORY_SCOPE_AGENT) != MAGIC)
      __builtin_amdgcn_s_sleep(1);
  }
  __syncthreads();
  __threadfence();

  // ---- E1 ----
#pragma unroll
  for (int rr = 0; rr < 2; rr++) {
    int o = blk * 8 + wave * 2 + rr;
    float pb[8];
    rowdot8<2048>(enc_w + (size_t)o * DIM, x, pb);
    float eb = enc_b[o];
#pragma unroll
    for (int b = 0; b < 8; b++) pb[b] = tanhf(pb[b] + eb);
    float myv = selLane8(pb);
    if (lane < 8) h1[lane * DIM + o] = myv;
  }
  postAdd(&bar[0]); pollGE(&bar[0], (unsigned)NB);

  // ---- E2 ----
#pragma unroll
  for (int rr = 0; rr < 2; rr++) {
    int o = blk * 8 + wave * 2 + rr;
    float pb[8];
    rowdot8<2048>(enc_w + (size_t)DIM * DIM + (size_t)o * DIM, h1, pb);
    float eb = enc_b[DIM + o];
#pragma unroll
    for (int b = 0; b < 8; b++) pb[b] = tanhf(pb[b] + eb);
    float myv = selLane8(pb);
    if (lane < 8) h2[lane * DIM + o] = myv;
  }
  postAdd(&bar[1]); pollGE(&bar[1], (unsigned)NB);

  // ---- E3 ----
  if (blk < 64) {
#pragma unroll
    for (int rr = 0; rr < 2; rr++) {
      int o = blk * 8 + wave * 2 + rr;
      float pb[8];
      rowdot8<2048>(out_w + (size_t)o * DIM, h2, pb);
      float ob = out_b[o];
#pragma unroll
      for (int b = 0; b < 8; b++) pb[b] += ob;
      float myv = selLane8(pb);
      if (lane < 8) img[lane * EMB + o] = myv;
    }
  } else if (blk < 128) {
    int local = blk - 64;
    int kk = lane * 8;
    float4 p0 = *(const float4*)(ph + kk);
    float4 p1 = *(const float4*)(ph + kk + 4);
    for (int r = 0; r < 6; r++) {
      int j = local * 24 + wave * 6 + r;
      const float4* w4 = (const float4*)(w_hh + (size_t)j * HID + kk);
      float s = dot4(p0, w4[0]) + dot4(p1, w4[1]);
#pragma unroll
      for (int m = 1; m < 64; m <<= 1) s += __shfl_xor(s, m, 64);
      float val = s + b_hh[j];
      if (lane < 8) gh[lane * G3 + j] = val;
    }
  } else if (blk < 192) {
    int local = blk - 128;
    for (int r = 0; r < 6; r++) {
      int j = local * 24 + wave * 6 + r;
      float val = b_ih[j];
      if (lane < 8) gi[lane * G3 + j] = val;
    }
  }
  for (int i = tid; i < 4096; i += NT) h_lds[i] = ph[i & 511];
  __syncthreads();
  postAdd(&bar[2]); pollGE(&bar[2], (unsigned)NB);

  const int v0 = blk * ROWS;
  const int k0 = lane * 8;
  const int rbeg = (wave * ROWS) / 4, rend = ((wave + 1) * ROWS) / 4;

  for (int t = 0; t < TLEN; ++t) {
    // 0) coalesced gumbel tile load
    for (int i = tid; i < ROWS * 8; i += NT) {
      int b = i / ROWS, vl = i - b * ROWS;
      gum_lds[vl * 8 + b] = gum[(size_t)t * (8 * VOC) + (size_t)b * VOC + v0 + vl];
    }
    // 1) wait for this step's gates
    if (t > 0) {
      if (tid == 0) {
        while (__hip_atomic_load(&gidone[t], __ATOMIC_ACQUIRE, __HIP_MEMORY_SCOPE_AGENT) < 64u)
          __builtin_amdgcn_s_sleep(1);
        while (__hip_atomic_load(&ghdone[t], __ATOMIC_ACQUIRE, __HIP_MEMORY_SCOPE_AGENT) < 64u)
          __builtin_amdgcn_s_sleep(1);
      }
      __syncthreads();
      __threadfence();
    }
    // 2) GRU elementwise update
    {
      int idx = tid * 16;
      int b = idx >> 9, k = idx & 511;
      const float* gib = gi + b * G3 + k;
      const float* ghb = gh + b * G3 + k;
      float* hpp = h_lds + b * 512 + k;
#pragma unroll
      for (int q = 0; q < 16; q += 4) {
        float4 ir = *(const float4*)(gib + q);
        float4 iz = *(const float4*)(gib + 512 + q);
        float4 in_ = *(const float4*)(gib + 1024 + q);
        float4 hr = *(const float4*)(ghb + q);
        float4 hz = *(const float4*)(ghb + 512 + q);
        float4 hn = *(const float4*)(ghb + 1024 + q);
        float4 hp = *(const float4*)(hpp + q);
        float4 hv;
        hv.x = gru_h(ir.x, iz.x, in_.x, hr.x, hz.x, hn.x, hp.x);
        hv.y = gru_h(ir.y, iz.y, in_.y, hr.y, hz.y, hn.y, hp.y);
        hv.z = gru_h(ir.z, iz.z, in_.z, hr.z, hz.z, hn.z, hp.z);
        hv.w = gru_h(ir.w, iz.w, in_.w, hr.w, hz.w, hn.w, hp.w);
        *(float4*)(hpp + q) = hv;
      }
    }
    __syncthreads();
    // 3) per-lane h fragments
    float4 hf[8][2];
#pragma unroll
    for (int b = 0; b < 8; b++) {
      hf[b][0] = *(const float4*)(h_lds + b * 512 + k0);
      hf[b][1] = *(const float4*)(h_lds + b * 512 + k0 + 4);
    }
    // 4) vocab rows, batched by 8 with hoisted loads (32 dwordx4 in flight/wave)
    float4 ea[8][2];
#pragma unroll
    for (int b = 0; b < 8; b++) { ea[b][0] = make_float4(0, 0, 0, 0); ea[b][1] = make_float4(0, 0, 0, 0); }
    float sums[8] = {0, 0, 0, 0, 0, 0, 0, 0};
    int r = rbeg;
    for (; r + 8 <= rend; r += 8) {
      float4 A0[8], A1[8], I0[8], I1[8];
#pragma unroll
      for (int u = 0; u < 8; u++) {
        int v = v0 + r + u;
        const float4* wo = (const float4*)(emb_out + (size_t)v * EMB + k0);
        A0[u] = wo[0]; A1[u] = wo[1];
        const float4* wi = (const float4*)(emb_in + (size_t)v * EMB + k0);
        I0[u] = wi[0]; I1[u] = wi[1];
      }
#pragma unroll
      for (int u = 0; u < 8; u++)
        vocabRow(r + u, A0[u], A1[u], I0[u], I1[u], hf, ea, sums, p_lds, gum_lds);
    }
    {  // predicated tail (wave-uniform rem), loads still batched
      int rem = rend - r;
      if (rem > 0) {
        float4 A0[8], A1[8], I0[8], I1[8];
#pragma unroll
        for (int u = 0; u < 8; u++) {
          int rr = (u < rem) ? (r + u) : r;
          int v = v0 + rr;
          const float4* wo = (const float4*)(emb_out + (size_t)v * EMB + k0);
          A0[u] = wo[0]; A1[u] = wo[1];
          const float4* wi = (const float4*)(emb_in + (size_t)v * EMB + k0);
          I0[u] = wi[0]; I1[u] = wi[1];
        }
#pragma unroll
        for (int u = 0; u < 8; u++)
          if (u < rem)
            vocabRow(r + u, A0[u], A1[u], I0[u], I1[u], hf, ea, sums, p_lds, gum_lds);
      }
    }
    // 5) cross-wave e reduce
    for (int w = 0; w < 4; w++) {
      if (wave == w) {
#pragma unroll
        for (int b = 0; b < 8; b++) {
          float4* d = (float4*)&red_e[b * 512 + k0];
          if (w == 0) { d[0] = ea[b][0]; d[1] = ea[b][1]; }
          else { d[0] = add4(d[0], ea[b][0]); d[1] = add4(d[1], ea[b][1]); }
        }
      }
      __syncthreads();
    }
    if (lane == 0) {
      *(float4*)&red_rs[wave * 8] = make_float4(sums[0], sums[1], sums[2], sums[3]);
      *(float4*)&red_rs[wave * 8 + 4] = make_float4(sums[4], sums[5], sums[6], sums[7]);
    }
    __syncthreads();
    // 6) publish e partial (chunked layout [chunk][src][64]) + rowsum partial
    {
      for (int i = tid; i < 1024; i += NT) {
        int p = i * 4;
        size_t dst = ((size_t)(p >> 6) << 14) + ((size_t)blk << 6) + (p & 63);
        *(float4*)(e_part + dst) = ((const float4*)red_e)[i];
      }
      if (tid == 0) {
        float4 lo = add4(add4(*(float4*)&red_rs[0], *(float4*)&red_rs[8]),
                         add4(*(float4*)&red_rs[16], *(float4*)&red_rs[24]));
        float4 hi = add4(add4(*(float4*)&red_rs[4], *(float4*)&red_rs[12]),
                         add4(*(float4*)&red_rs[20], *(float4*)&red_rs[28]));
        *(float4*)&rs_part[blk * 8] = lo;
        *(float4*)&rs_part[blk * 8 + 4] = hi;
      }
    }
    postAdd(&arrive[t]);

    // ---- roles ----
    if (blk < 64 && t < TLEN - 1) {  // e reducers: coalesced chunk reads
      pollGE(&arrive[t], (unsigned)NB);
      const int e = tid & 63, ig = tid >> 6;
      const float* base = e_part + ((size_t)blk << 14);
      float ssum = 0.0f;
#pragma unroll 8
      for (int j = 0; j < 64; ++j) ssum += base[(size_t)(ig * 64 + j) * 64 + e];
      red_e[tid] = ssum;
      __syncthreads();
      if (tid < 64) {
        float tot = red_e[tid] + red_e[tid + 64] + red_e[tid + 128] + red_e[tid + 192];
        int og = blk * 64 + tid;
        sbuf[og] = tot * img[og];
      }
      postAdd(&sdone[t]);
    }
    if (blk == 64) {  // rowsum reducer
      pollGE(&arrive[t], (unsigned)NB);
      int b = tid & 7, g = tid >> 3;
      float s = 0.0f;
#pragma unroll
      for (int i = 0; i < 8; i++) s += rs_part[(size_t)(g + 32 * i) * 8 + b];
      red_e[tid] = s;
      __syncthreads();
      if (tid < 8) {
        float tot = 0.0f;
#pragma unroll
        for (int g2 = 0; g2 < 32; ++g2) tot += red_e[g2 * 8 + tid];
        rs_tot[t * 8 + tid] = tot;
      }
      __threadfence();
      __syncthreads();
      if (tid == 0)
        __hip_atomic_store(&rsready[t], 1u, __ATOMIC_RELEASE, __HIP_MEMORY_SCOPE_AGENT);
    }
    if (blk >= 65 && blk < 129 && t < TLEN - 1) {  // gi producers
      pollGE(&sdone[t], 64u);
      pollGE(&rsready[t], 1u);
      float inv[8];
#pragma unroll
      for (int b = 0; b < 8; b++) inv[b] = 1.0f / rs_tot[t * 8 + b];
      float4 sf[8][2];
#pragma unroll
      for (int b = 0; b < 8; b++) {
        sf[b][0] = *(const float4*)(sbuf + b * 512 + k0);
        sf[b][1] = *(const float4*)(sbuf + b * 512 + k0 + 4);
      }
      int local = blk - 65;
      for (int r2 = 0; r2 < 6; r2++) {
        int j = local * 24 + wave * 6 + r2;
        const float4* w4 = (const float4*)(w_ih + (size_t)j * HID + k0);
        float4 w0 = w4[0], w1 = w4[1];
        float pb[8];
#pragma unroll
        for (int b = 0; b < 8; b++) pb[b] = dot4(sf[b][0], w0) + dot4(sf[b][1], w1);
#pragma unroll
        for (int m = 1; m < 64; m <<= 1) {
#pragma unroll
          for (int b = 0; b < 8; b++) pb[b] += __shfl_xor(pb[b], m, 64);
        }
        float bi = b_ih[j];
#pragma unroll
        for (int b = 0; b < 8; b++) pb[b] = inv[b] * pb[b] + bi;
        float myv = selLane8(pb);
        if (lane < 8) gi[lane * G3 + j] = myv;
      }
      postAdd(&gidone[t + 1]);
    }
    if (blk >= 129 && blk < 193 && t < TLEN - 1) {  // gh producers
      pollGE(&arrive[t], (unsigned)NB);
      int local = blk - 129;
      for (int r2 = 0; r2 < 6; r2++) {
        int j = local * 24 + wave * 6 + r2;
        const float4* w4 = (const float4*)(w_hh + (size_t)j * HID + k0);
        float4 w0 = w4[0], w1 = w4[1];
        float pb[8];
#pragma unroll
        for (int b = 0; b < 8; b++) pb[b] = dot4(hf[b][0], w0) + dot4(hf[b][1], w1);
#pragma unroll
        for (int m = 1; m < 64; m <<= 1) {
#pragma unroll
          for (int b = 0; b < 8; b++) pb[b] += __shfl_xor(pb[b], m, 64);
        }
        float bh = b_hh[j];
#pragma unroll
        for (int b = 0; b < 8; b++) pb[b] += bh;
        float myv = selLane8(pb);
        if (lane < 8) gh[lane * G3 + j] = myv;
      }
      postAdd(&ghdone[t + 1]);
    }
    // ---- x_t normalize + write ----
    pollGE(&rsready[t], 1u);
    if (tid < 8) inv_lds[tid] = 1.0f / rs_tot[t * 8 + tid];
    __syncthreads();
    {
      for (int i = tid; i < ROWS * 8; i += NT) {
        int b = i / ROWS, vl = i - b * ROWS;
        out[(size_t)b * ((size_t)TLEN * VOC) + (size_t)t * VOC + v0 + vl] =
            p_lds[vl * 8 + b] * inv_lds[b];
      }
    }
  }
}

extern "C" void kernel_launch(void* const* d_in, const int* in_sizes, int n_in,
                              void* d_out, int out_size, void* d_ws, size_t ws_size,
                              hipStream_t stream) {
  const float* x = (const float*)d_in[0];
  const float* enc_w = (const float*)d_in[1];
  const float* enc_b = (const float*)d_in[2];
  const float* out_w = (const float*)d_in[3];
  const float* out_b = (const float*)d_in[4];
  const float* emb_out = (const float*)d_in[5];
  const float* emb_in = (const float*)d_in[6];
  const float* ph = (const float*)d_in[7];
  const float* w_ih = (const float*)d_in[8];
  const float* b_ih = (const float*)d_in[9];
  const float* w_hh = (const float*)d_in[10];
  const float* b_hh = (const float*)d_in[11];
  const float* gum = (const float*)d_in[12];
  float* out = (float*)d_out;
  float* ws = (float*)d_ws;

  InformedRnnSenderFixedLengthGS_48704929136907_kernel<<<dim3(NB), dim3(NT), 0, stream>>>(
      x, enc_w, enc_b, out_w, out_b, emb_out, emb_in, ph, w_ih, b_ih, w_hh, b_hh, gum,
      out, ws);
}

// Round 4
// 4344.133 us; speedup vs baseline: 2.1485x; 1.8167x over previous
//
#include <hip/hip_runtime.h>
#include <math.h>

constexpr int DIM = 2048, EMB = 512, HID = 512, VOC = 32000, TLEN = 32, G3 = 1536;
constexpr int NB = 256;     // blocks; 1/CU co-resident (grid <= 256 CUs)
constexpr int NT = 256;     // threads/block (4 waves)
constexpr int ROWS = 125;   // vocab rows per block
constexpr unsigned MAGIC = 0x13579BDFu;

// ---- workspace layout (float units) ----
constexpr size_t W_H1  = 0;                          // [8][2048]
constexpr size_t W_H2  = W_H1 + 8 * 2048;            // [8][2048]
constexpr size_t W_IMG = W_H2 + 8 * 2048;            // [8][512]
constexpr size_t W_GI  = W_IMG + 8 * 512;            // [8][1536] giU (unnormalized, no bias)
constexpr size_t W_GH  = W_GI + 8 * 1536;            // [8][1536] gh (with bias)
constexpr size_t W_S   = W_GH + 8 * 1536;            // [8][512]  (sum e)*img, unnormalized
constexpr size_t W_RSP = W_S + 8 * 512;              // [256][8] rowsum partials
constexpr size_t W_RST = W_RSP + (size_t)NB * 8;     // [33][8]  rowsum totals
constexpr size_t W_EP  = W_RST + 33 * 8;             // [64 chunks][256 src][64] e partials
constexpr size_t W_AF  = W_EP + (size_t)NB * 4096;   // 256 slots x 16 uints (arrive)
constexpr size_t W_SF  = W_AF + 256 * 16;            // 64 slots (sdone)
constexpr size_t W_GF  = W_SF + 64 * 16;             // 64 slots (gi done)
constexpr size_t W_HF  = W_GF + 64 * 16;             // 64 slots (gh done)
constexpr size_t W_RF  = W_HF + 64 * 16;             // 1 slot (rowsum ready)
constexpr size_t W_RDY = W_RF + 16;                  // 1 slot (init handshake)
constexpr int FLAG_WORDS = 256 * 16 + 64 * 16 * 3 + 16;  // zeroed region (excl. ready)

__device__ __forceinline__ float dot4(float4 a, float4 b) {
  return a.x * b.x + a.y * b.y + a.z * b.z + a.w * b.w;
}
__device__ __forceinline__ float4 fma4(float4 acc, float s, float4 v) {
  acc.x += s * v.x; acc.y += s * v.y; acc.z += s * v.z; acc.w += s * v.w; return acc;
}
__device__ __forceinline__ float4 add4(float4 a, float4 b) {
  a.x += b.x; a.y += b.y; a.z += b.z; a.w += b.w; return a;
}
__device__ __forceinline__ float sigm(float x) { return 1.0f / (1.0f + __expf(-x)); }
__device__ __forceinline__ float selLane8(const float pb[8]) {
  int lane = threadIdx.x & 63;
  float r = 0.0f;
#pragma unroll
  for (int b = 0; b < 8; b++) r = (lane == b) ? pb[b] : r;
  return r;
}

template <int KLEN>
__device__ __forceinline__ void rowdot8(const float* __restrict__ wrow,
                                        const float* __restrict__ xsrc, float pb[8]) {
  constexpr int PER = KLEN / 64;
  constexpr int NF4 = PER / 4;
  int lane = threadIdx.x & 63;
  int k0 = lane * PER;
  const float4* w4 = (const float4*)(wrow + k0);
  float4 wv[NF4];
#pragma unroll
  for (int i = 0; i < NF4; i++) wv[i] = w4[i];
#pragma unroll
  for (int b = 0; b < 8; b++) {
    const float4* x4 = (const float4*)(xsrc + b * KLEN + k0);
    float s = 0.0f;
#pragma unroll
    for (int i = 0; i < NF4; i++) s += dot4(x4[i], wv[i]);
    pb[b] = s;
  }
#pragma unroll
  for (int m = 1; m < 64; m <<= 1) {
#pragma unroll
    for (int b = 0; b < 8; b++) pb[b] += __shfl_xor(pb[b], m, 64);
  }
}

// producer: block-wide stores drained at barrier, single wbl2, release store
__device__ __forceinline__ void postSlot(unsigned* slot, unsigned val) {
  __syncthreads();
  if (threadIdx.x == 0) {
    __threadfence();
    __hip_atomic_store(slot, val, __ATOMIC_RELEASE, __HIP_MEMORY_SCOPE_AGENT);
  }
}
// consumer: thread i polls slot i (parallel, read-only, no contention)
__device__ __forceinline__ void pollSlots(const unsigned* slots, int n, unsigned tgt) {
  int tid = threadIdx.x;
  if (tid < n) {
    const unsigned* p = slots + (size_t)tid * 16;
    while (__hip_atomic_load(p, __ATOMIC_RELAXED, __HIP_MEMORY_SCOPE_AGENT) < tgt)
      __builtin_amdgcn_s_sleep(1);
  }
  __syncthreads();
  __threadfence();
}

// one vocab row: logits dot + butterfly + gumbel/exp + p store + e-accum
__device__ __forceinline__ void vocabRow(int r, float4 a0, float4 a1, float4 i0, float4 i1,
                                         const float4 hf[8][2], float4 ea[8][2],
                                         float sums[8], float* __restrict__ p_lds,
                                         const float* __restrict__ gum_lds) {
  int lane = threadIdx.x & 63;
  float pb[8];
#pragma unroll
  for (int b = 0; b < 8; b++) pb[b] = dot4(hf[b][0], a0) + dot4(hf[b][1], a1);
#pragma unroll
  for (int m = 1; m < 64; m <<= 1) {
#pragma unroll
    for (int b = 0; b < 8; b++) pb[b] += __shfl_xor(pb[b], m, 64);
  }
#pragma unroll
  for (int b = 0; b < 8; b++) {
    pb[b] = __expf(pb[b] + gum_lds[r * 8 + b]);
    sums[b] += pb[b];
  }
  if (lane == 0) {
    *(float4*)&p_lds[r * 8] = make_float4(pb[0], pb[1], pb[2], pb[3]);
    *(float4*)&p_lds[r * 8 + 4] = make_float4(pb[4], pb[5], pb[6], pb[7]);
  }
#pragma unroll
  for (int b = 0; b < 8; b++) {
    ea[b][0] = fma4(ea[b][0], pb[b], i0);
    ea[b][1] = fma4(ea[b][1], pb[b], i1);
  }
}

__global__ void __launch_bounds__(NT, 1)
InformedRnnSenderFixedLengthGS_48704929136907_kernel(
    const float* __restrict__ x, const float* __restrict__ enc_w,
    const float* __restrict__ enc_b, const float* __restrict__ out_w,
    const float* __restrict__ out_b, const float* __restrict__ emb_out,
    const float* __restrict__ emb_in, const float* __restrict__ ph,
    const float* __restrict__ w_ih, const float* __restrict__ b_ih,
    const float* __restrict__ w_hh, const float* __restrict__ b_hh,
    const float* __restrict__ gum, float* __restrict__ out, float* __restrict__ ws) {
  const int tid = threadIdx.x, blk = blockIdx.x;
  const int lane = tid & 63, wave = tid >> 6;

  float* h1 = ws + W_H1;
  float* h2 = ws + W_H2;
  float* img = ws + W_IMG;
  float* giU = ws + W_GI;
  float* gh = ws + W_GH;
  float* sbuf = ws + W_S;
  float* rs_part = ws + W_RSP;
  float* rs_tot = ws + W_RST;
  float* e_part = ws + W_EP;
  unsigned* aflag = (unsigned*)(ws + W_AF);
  unsigned* sflag = (unsigned*)(ws + W_SF);
  unsigned* gflag = (unsigned*)(ws + W_GF);
  unsigned* hflag = (unsigned*)(ws + W_HF);
  unsigned* rsflag = (unsigned*)(ws + W_RF);
  unsigned* ready = (unsigned*)(ws + W_RDY);

  __shared__ float h_lds[4096];      // [8][512] hidden state
  __shared__ float red_e[4096];      // reduce scratch
  __shared__ float p_lds[ROWS * 8];
  __shared__ float gum_lds[ROWS * 8];
  __shared__ float bih_lds[G3];
  __shared__ float red_rs[32];
  __shared__ float inv_lds[8];

  // ---- init handshake: block 0 zeroes flags, then releases MAGIC ----
  if (blk == 0) {
    for (int i = tid; i < FLAG_WORDS; i += NT) aflag[i] = 0u;
    __syncthreads();
    if (tid == 0) {
      __threadfence();
      __hip_atomic_store(ready, MAGIC, __ATOMIC_RELEASE, __HIP_MEMORY_SCOPE_AGENT);
    }
  }
  if (tid == 0) {
    while (__hip_atomic_load(ready, __ATOMIC_ACQUIRE, __HIP_MEMORY_SCOPE_AGENT) != MAGIC)
      __builtin_amdgcn_s_sleep(1);
  }
  __syncthreads();
  __threadfence();

  // ---- E1: h1 = tanh(x @ enc_w0^T + b0) ----
#pragma unroll
  for (int rr = 0; rr < 2; rr++) {
    int o = blk * 8 + wave * 2 + rr;
    float pb[8];
    rowdot8<2048>(enc_w + (size_t)o * DIM, x, pb);
    float eb = enc_b[o];
#pragma unroll
    for (int b = 0; b < 8; b++) pb[b] = tanhf(pb[b] + eb);
    float myv = selLane8(pb);
    if (lane < 8) h1[lane * DIM + o] = myv;
  }
  postSlot(&aflag[blk * 16], 1u);
  pollSlots(aflag, 256, 1u);

  // ---- E2 ----
#pragma unroll
  for (int rr = 0; rr < 2; rr++) {
    int o = blk * 8 + wave * 2 + rr;
    float pb[8];
    rowdot8<2048>(enc_w + (size_t)DIM * DIM + (size_t)o * DIM, h1, pb);
    float eb = enc_b[DIM + o];
#pragma unroll
    for (int b = 0; b < 8; b++) pb[b] = tanhf(pb[b] + eb);
    float myv = selLane8(pb);
    if (lane < 8) h2[lane * DIM + o] = myv;
  }
  postSlot(&aflag[blk * 16], 2u);
  pollSlots(aflag, 256, 2u);

  // ---- E3: img (blk<64), gh0 with bias (64..127), giU0=0 (128..191) ----
  if (blk < 64) {
#pragma unroll
    for (int rr = 0; rr < 2; rr++) {
      int o = blk * 8 + wave * 2 + rr;
      float pb[8];
      rowdot8<2048>(out_w + (size_t)o * DIM, h2, pb);
      float ob = out_b[o];
#pragma unroll
      for (int b = 0; b < 8; b++) pb[b] += ob;
      float myv = selLane8(pb);
      if (lane < 8) img[lane * EMB + o] = myv;
    }
  } else if (blk < 128) {
    int local = blk - 64;
    int kk = lane * 8;
    float4 p0 = *(const float4*)(ph + kk);
    float4 p1 = *(const float4*)(ph + kk + 4);
    for (int r = 0; r < 6; r++) {
      int j = local * 24 + wave * 6 + r;
      const float4* w4 = (const float4*)(w_hh + (size_t)j * HID + kk);
      float s = dot4(p0, w4[0]) + dot4(p1, w4[1]);
#pragma unroll
      for (int m = 1; m < 64; m <<= 1) s += __shfl_xor(s, m, 64);
      float val = s + b_hh[j];
      if (lane < 8) gh[lane * G3 + j] = val;
    }
  } else if (blk < 192) {
    int local = blk - 128;
    for (int r = 0; r < 6; r++) {
      int j = local * 24 + wave * 6 + r;
      if (lane < 8) giU[lane * G3 + j] = 0.0f;  // e0 == 0
    }
  }
  for (int i = tid; i < 4096; i += NT) h_lds[i] = ph[i & 511];
  for (int i = tid; i < G3; i += NT) bih_lds[i] = b_ih[i];
  if (tid < 8) inv_lds[tid] = 1.0f;  // step-0 giU is zero, inv moot
  __syncthreads();
  postSlot(&aflag[blk * 16], 3u);
  pollSlots(aflag, 256, 3u);

  const int v0 = blk * ROWS;
  const int k0 = lane * 8;
  const int rbeg = (wave * ROWS) / 4, rend = ((wave + 1) * ROWS) / 4;

  for (int t = 0; t < TLEN; ++t) {
    // 0) coalesced gumbel tile load (in flight during the gate wait)
    for (int i = tid; i < ROWS * 8; i += NT) {
      int b = i / ROWS, vl = i - b * ROWS;
      gum_lds[vl * 8 + b] = gum[(size_t)t * (8 * VOC) + (size_t)b * VOC + v0 + vl];
    }
    // 1) wait for this step's gates (parallel slot poll)
    if (t > 0) {
      if (tid < 64) {
        const unsigned* p = gflag + (size_t)tid * 16;
        while (__hip_atomic_load(p, __ATOMIC_RELAXED, __HIP_MEMORY_SCOPE_AGENT) < (unsigned)t)
          __builtin_amdgcn_s_sleep(1);
      } else if (tid < 128) {
        const unsigned* p = hflag + (size_t)(tid - 64) * 16;
        while (__hip_atomic_load(p, __ATOMIC_RELAXED, __HIP_MEMORY_SCOPE_AGENT) < (unsigned)t)
          __builtin_amdgcn_s_sleep(1);
      }
      __syncthreads();
      __threadfence();
    }
    // 2) GRU elementwise update: gi = inv_prev[b]*giU + b_ih ; gh has bias already
    {
      int idx = tid * 16;
      int b = idx >> 9, k = idx & 511;
      float invb = inv_lds[b];
      const float* gib = giU + b * G3 + k;
      const float* ghb = gh + b * G3 + k;
      float* hpp = h_lds + b * 512 + k;
#pragma unroll
      for (int q = 0; q < 16; q += 4) {
        float4 iru = *(const float4*)(gib + q);
        float4 izu = *(const float4*)(gib + 512 + q);
        float4 inu = *(const float4*)(gib + 1024 + q);
        float4 br = *(const float4*)(bih_lds + k + q);
        float4 bz = *(const float4*)(bih_lds + 512 + k + q);
        float4 bn = *(const float4*)(bih_lds + 1024 + k + q);
        float4 hr = *(const float4*)(ghb + q);
        float4 hz = *(const float4*)(ghb + 512 + q);
        float4 hn = *(const float4*)(ghb + 1024 + q);
        float4 hp = *(const float4*)(hpp + q);
        float4 hv;
        {
          float r0 = sigm(invb * iru.x + br.x + hr.x), z0 = sigm(invb * izu.x + bz.x + hz.x);
          float n0 = tanhf(invb * inu.x + bn.x + r0 * hn.x);
          hv.x = (1.0f - z0) * n0 + z0 * hp.x;
          r0 = sigm(invb * iru.y + br.y + hr.y); z0 = sigm(invb * izu.y + bz.y + hz.y);
          n0 = tanhf(invb * inu.y + bn.y + r0 * hn.y);
          hv.y = (1.0f - z0) * n0 + z0 * hp.y;
          r0 = sigm(invb * iru.z + br.z + hr.z); z0 = sigm(invb * izu.z + bz.z + hz.z);
          n0 = tanhf(invb * inu.z + bn.z + r0 * hn.z);
          hv.z = (1.0f - z0) * n0 + z0 * hp.z;
          r0 = sigm(invb * iru.w + br.w + hr.w); z0 = sigm(invb * izu.w + bz.w + hz.w);
          n0 = tanhf(invb * inu.w + bn.w + r0 * hn.w);
          hv.w = (1.0f - z0) * n0 + z0 * hp.w;
        }
        *(float4*)(hpp + q) = hv;
      }
    }
    __syncthreads();
    // 3) per-lane h fragments
    float4 hf[8][2];
#pragma unroll
    for (int b = 0; b < 8; b++) {
      hf[b][0] = *(const float4*)(h_lds + b * 512 + k0);
      hf[b][1] = *(const float4*)(h_lds + b * 512 + k0 + 4);
    }
    // 4) vocab rows, batched by 8 with hoisted loads
    float4 ea[8][2];
#pragma unroll
    for (int b = 0; b < 8; b++) { ea[b][0] = make_float4(0, 0, 0, 0); ea[b][1] = make_float4(0, 0, 0, 0); }
    float sums[8] = {0, 0, 0, 0, 0, 0, 0, 0};
    int r = rbeg;
    for (; r + 8 <= rend; r += 8) {
      float4 A0[8], A1[8], I0[8], I1[8];
#pragma unroll
      for (int u = 0; u < 8; u++) {
        int v = v0 + r + u;
        const float4* wo = (const float4*)(emb_out + (size_t)v * EMB + k0);
        A0[u] = wo[0]; A1[u] = wo[1];
        const float4* wi = (const float4*)(emb_in + (size_t)v * EMB + k0);
        I0[u] = wi[0]; I1[u] = wi[1];
      }
#pragma unroll
      for (int u = 0; u < 8; u++)
        vocabRow(r + u, A0[u], A1[u], I0[u], I1[u], hf, ea, sums, p_lds, gum_lds);
    }
    {
      int rem = rend - r;
      if (rem > 0) {
        float4 A0[8], A1[8], I0[8], I1[8];
#pragma unroll
        for (int u = 0; u < 8; u++) {
          int rr = (u < rem) ? (r + u) : r;
          int v = v0 + rr;
          const float4* wo = (const float4*)(emb_out + (size_t)v * EMB + k0);
          A0[u] = wo[0]; A1[u] = wo[1];
          const float4* wi = (const float4*)(emb_in + (size_t)v * EMB + k0);
          I0[u] = wi[0]; I1[u] = wi[1];
        }
#pragma unroll
        for (int u = 0; u < 8; u++)
          if (u < rem)
            vocabRow(r + u, A0[u], A1[u], I0[u], I1[u], hf, ea, sums, p_lds, gum_lds);
      }
    }
    // 5) cross-wave e reduce
    for (int w = 0; w < 4; w++) {
      if (wave == w) {
#pragma unroll
        for (int b = 0; b < 8; b++) {
          float4* d = (float4*)&red_e[b * 512 + k0];
          if (w == 0) { d[0] = ea[b][0]; d[1] = ea[b][1]; }
          else { d[0] = add4(d[0], ea[b][0]); d[1] = add4(d[1], ea[b][1]); }
        }
      }
      __syncthreads();
    }
    if (lane == 0) {
      *(float4*)&red_rs[wave * 8] = make_float4(sums[0], sums[1], sums[2], sums[3]);
      *(float4*)&red_rs[wave * 8 + 4] = make_float4(sums[4], sums[5], sums[6], sums[7]);
    }
    __syncthreads();
    // 6) publish e partial (chunked [chunk][src][64]) + rowsum partial, then arrive
    {
      for (int i = tid; i < 1024; i += NT) {
        int p = i * 4;
        size_t dst = ((size_t)(p >> 6) << 14) + ((size_t)blk << 6) + (p & 63);
        *(float4*)(e_part + dst) = ((const float4*)red_e)[i];
      }
      if (tid == 0) {
        float4 lo = add4(add4(*(float4*)&red_rs[0], *(float4*)&red_rs[8]),
                         add4(*(float4*)&red_rs[16], *(float4*)&red_rs[24]));
        float4 hi = add4(add4(*(float4*)&red_rs[4], *(float4*)&red_rs[12]),
                         add4(*(float4*)&red_rs[20], *(float4*)&red_rs[28]));
        *(float4*)&rs_part[blk * 8] = lo;
        *(float4*)&rs_part[blk * 8 + 4] = hi;
      }
    }
    postSlot(&aflag[blk * 16], (unsigned)(t + 4));

    // ---- roles ----
    if (blk < 64 && t < TLEN - 1) {  // e reducers -> sbuf = (sum e)*img (unnormalized)
      pollSlots(aflag, 256, (unsigned)(t + 4));
      const int e = tid & 63, ig = tid >> 6;
      const float* base = e_part + ((size_t)blk << 14);
      float ssum = 0.0f;
#pragma unroll 8
      for (int j = 0; j < 64; ++j) ssum += base[(size_t)(ig * 64 + j) * 64 + e];
      red_e[tid] = ssum;
      __syncthreads();
      if (tid < 64) {
        float tot = red_e[tid] + red_e[tid + 64] + red_e[tid + 128] + red_e[tid + 192];
        int og = blk * 64 + tid;
        sbuf[og] = tot * img[og];
      }
      postSlot(&sflag[blk * 16], (unsigned)(t + 1));
    }
    if (blk == 64) {  // rowsum reducer
      pollSlots(aflag, 256, (unsigned)(t + 4));
      int b = tid & 7, g = tid >> 3;
      float s = 0.0f;
#pragma unroll
      for (int i = 0; i < 8; i++) s += rs_part[(size_t)(g + 32 * i) * 8 + b];
      red_e[tid] = s;
      __syncthreads();
      if (tid < 8) {
        float tot = 0.0f;
#pragma unroll
        for (int g2 = 0; g2 < 32; ++g2) tot += red_e[g2 * 8 + tid];
        rs_tot[t * 8 + tid] = tot;
      }
      postSlot(&rsflag[0], (unsigned)(t + 1));
    }
    if (blk >= 65 && blk < 129 && t < TLEN - 1) {  // giU producers (no rowsum dep!)
      pollSlots(sflag, 64, (unsigned)(t + 1));
      float4 sf[8][2];
#pragma unroll
      for (int b = 0; b < 8; b++) {
        sf[b][0] = *(const float4*)(sbuf + b * 512 + k0);
        sf[b][1] = *(const float4*)(sbuf + b * 512 + k0 + 4);
      }
      int local = blk - 65;
      for (int r2 = 0; r2 < 6; r2++) {
        int j = local * 24 + wave * 6 + r2;
        const float4* w4 = (const float4*)(w_ih + (size_t)j * HID + k0);
        float4 w0 = w4[0], w1 = w4[1];
        float pb[8];
#pragma unroll
        for (int b = 0; b < 8; b++) pb[b] = dot4(sf[b][0], w0) + dot4(sf[b][1], w1);
#pragma unroll
        for (int m = 1; m < 64; m <<= 1) {
#pragma unroll
          for (int b = 0; b < 8; b++) pb[b] += __shfl_xor(pb[b], m, 64);
        }
        float myv = selLane8(pb);
        if (lane < 8) giU[lane * G3 + j] = myv;
      }
      postSlot(&gflag[(blk - 65) * 16], (unsigned)(t + 1));
    }
    if (blk >= 129 && blk < 193 && t < TLEN - 1) {  // gh producers (with bias)
      pollSlots(aflag, 256, (unsigned)(t + 4));  // WAR: all blocks read gh(t) already
      int local = blk - 129;
      for (int r2 = 0; r2 < 6; r2++) {
        int j = local * 24 + wave * 6 + r2;
        const float4* w4 = (const float4*)(w_hh + (size_t)j * HID + k0);
        float4 w0 = w4[0], w1 = w4[1];
        float pb[8];
#pragma unroll
        for (int b = 0; b < 8; b++) pb[b] = dot4(hf[b][0], w0) + dot4(hf[b][1], w1);
#pragma unroll
        for (int m = 1; m < 64; m <<= 1) {
#pragma unroll
          for (int b = 0; b < 8; b++) pb[b] += __shfl_xor(pb[b], m, 64);
        }
        float bh = b_hh[j];
#pragma unroll
        for (int b = 0; b < 8; b++) pb[b] += bh;
        float myv = selLane8(pb);
        if (lane < 8) gh[lane * G3 + j] = myv;
      }
      postSlot(&hflag[(blk - 129) * 16], (unsigned)(t + 1));
    }
    // ---- x_t normalize + write (all blocks); also latches inv for next GRU ----
    if (tid == 0) {
      while (__hip_atomic_load(rsflag, __ATOMIC_RELAXED, __HIP_MEMORY_SCOPE_AGENT) <
             (unsigned)(t + 1))
        __builtin_amdgcn_s_sleep(1);
    }
    __syncthreads();
    __threadfence();
    if (tid < 8) inv_lds[tid] = 1.0f / rs_tot[t * 8 + tid];
    __syncthreads();
    for (int i = tid; i < ROWS * 8; i += NT) {
      int b = i / ROWS, vl = i - b * ROWS;
      out[(size_t)b * ((size_t)TLEN * VOC) + (size_t)t * VOC + v0 + vl] =
          p_lds[vl * 8 + b] * inv_lds[b];
    }
  }
}

extern "C" void kernel_launch(void* const* d_in, const int* in_sizes, int n_in,
                              void* d_out, int out_size, void* d_ws, size_t ws_size,
                              hipStream_t stream) {
  const float* x = (const float*)d_in[0];
  const float* enc_w = (const float*)d_in[1];
  const float* enc_b = (const float*)d_in[2];
  const float* out_w = (const float*)d_in[3];
  const float* out_b = (const float*)d_in[4];
  const float* emb_out = (const float*)d_in[5];
  const float* emb_in = (const float*)d_in[6];
  const float* ph = (const float*)d_in[7];
  const float* w_ih = (const float*)d_in[8];
  const float* b_ih = (const float*)d_in[9];
  const float* w_hh = (const float*)d_in[10];
  const float* b_hh = (const float*)d_in[11];
  const float* gum = (const float*)d_in[12];
  float* out = (float*)d_out;
  float* ws = (float*)d_ws;

  InformedRnnSenderFixedLengthGS_48704929136907_kernel<<<dim3(NB), dim3(NT), 0, stream>>>(
      x, enc_w, enc_b, out_w, out_b, emb_out, emb_in, ph, w_ih, b_ih, w_hh, b_hh, gum,
      out, ws);
}